// Round 1
// baseline (123.906 us; speedup 1.0000x reference)
//
#include <hip/hip_runtime.h>
#include <stdint.h>

// ComplexWaveformSystem: sim[b,t] = |rx[b,:] . conj(ifft_ortho(freq[t,:]))|^2 / temp
// B = 8192 (batch), T = 8192 (tokens), L = 128, K = 2L = 256 (re/im interleaved)

#define T_TOKENS 8192
#define B_BATCH  8192
#define L_SEQ    128
#define KDIM     256

typedef __bf16 bf16x8 __attribute__((ext_vector_type(8)));
typedef float  f32x4  __attribute__((ext_vector_type(4)));
typedef unsigned int u32x4 __attribute__((ext_vector_type(4)));

// float -> bf16 round-to-nearest-even (inputs are finite; no NaN path needed)
__device__ __forceinline__ unsigned short f2bf(float f) {
  unsigned int u = __builtin_bit_cast(unsigned int, f);
  u += 0x7FFFu + ((u >> 16) & 1u);
  return (unsigned short)(u >> 16);
}

// ---------------- prep 1: bank[t,l] = (1/sqrt(128)) sum_k freq[t,k] e^{+2pi i k l/128}
// store interleaved bf16: B2[t][2l] = bank_r, B2[t][2l+1] = bank_i  (packed as u32)
__global__ void build_bank_kernel(const float* __restrict__ fr,
                                  const float* __restrict__ fi,
                                  unsigned int* __restrict__ B2) {
  __shared__ float  sfr[L_SEQ], sfi[L_SEQ];
  __shared__ float2 stw[L_SEQ];
  const int t = blockIdx.x, l = threadIdx.x;
  sfr[l] = fr[t * L_SEQ + l];
  sfi[l] = fi[t * L_SEQ + l];
  float sn, cs;
  __sincosf(6.283185307179586f * (float)l * (1.0f / 128.0f), &sn, &cs);
  stw[l] = make_float2(cs, sn);
  __syncthreads();
  float br = 0.f, bi = 0.f;
#pragma unroll 8
  for (int k = 0; k < L_SEQ; ++k) {
    const float2 tw = stw[(k * l) & 127];
    const float xr = sfr[k], xi = sfi[k];
    br = fmaf(xr, tw.x, br); br = fmaf(-xi, tw.y, br);
    bi = fmaf(xr, tw.y, bi); bi = fmaf(xi, tw.x, bi);
  }
  const float sc = 0.08838834764831845f;  // 1/sqrt(128): norm="ortho"
  const unsigned int lo = f2bf(br * sc);
  const unsigned int hi = f2bf(bi * sc);
  B2[t * L_SEQ + l] = lo | (hi << 16);
}

// ---------------- prep 2: A2[b][2l] = rx_r, A2[b][2l+1] = rx_i (packed u32)
__global__ void build_a_kernel(const float* __restrict__ rr,
                               const float* __restrict__ ri,
                               unsigned int* __restrict__ A2) {
  const int i = blockIdx.x * 256 + threadIdx.x;  // exactly B*L threads
  const unsigned int lo = f2bf(rr[i]);
  const unsigned int hi = f2bf(ri[i]);
  A2[i] = lo | (hi << 16);
}

// ---------------- GEMM with fused |.|^2 epilogue
typedef const __attribute__((address_space(1))) unsigned int* gas_u32p;
typedef __attribute__((address_space(3))) unsigned int* las_u32p;

__device__ __forceinline__ void gl_lds16(const void* g, void* l) {
  // 16B per lane, LDS dest = wave-uniform base + lane*16
  __builtin_amdgcn_global_load_lds((gas_u32p)g, (las_u32p)l, 16, 0, 0);
}

// A'[2l] = A[2l+1], A'[2l+1] = -A[2l]  (per 32-bit word: swap halves, negate new hi)
__device__ __forceinline__ bf16x8 make_imag(bf16x8 a) {
  u32x4 u = __builtin_bit_cast(u32x4, a);
#pragma unroll
  for (int i = 0; i < 4; ++i)
    u[i] = ((u[i] >> 16) | (u[i] << 16)) ^ 0x80000000u;
  return __builtin_bit_cast(bf16x8, u);
}

__global__ __launch_bounds__(256, 2) void gemm_kernel(
    const unsigned short* __restrict__ A2,
    const unsigned short* __restrict__ B2,
    const float* __restrict__ temp,
    float* __restrict__ out) {
  // 128x128 tile, 4 waves (2x2), each wave 64x64; BK=64, 4 K-steps, LDS dbuf
  __shared__ __align__(16) unsigned short sA[2][128 * 64];
  __shared__ __align__(16) unsigned short sB[2][128 * 64];

  const int tid  = threadIdx.x;
  const int lane = tid & 63;
  const int wid  = tid >> 6;

  // XCD-bijective swizzle: 4096 blocks % 8 == 0, 512 contiguous per XCD
  const int bid  = blockIdx.x;
  const int swz  = (bid & 7) * 512 + (bid >> 3);
  const int brow = swz >> 6;
  const int bcol = swz & 63;
  const int wr = wid >> 1, wc = wid & 1;

  const unsigned short* Abase = A2 + (size_t)brow * 128 * KDIM;
  const unsigned short* Bbase = B2 + (size_t)bcol * 128 * KDIM;

  f32x4 accre[4][4], accim[4][4];
#pragma unroll
  for (int m = 0; m < 4; ++m)
#pragma unroll
    for (int n = 0; n < 4; ++n) {
      accre[m][n] = f32x4{0.f, 0.f, 0.f, 0.f};
      accim[m][n] = f32x4{0.f, 0.f, 0.f, 0.f};
    }

  // stage one 128x64 K-slab of A and B into LDS buffer `buf`
  auto stage = [&](int ks, int buf) {
#pragma unroll
    for (int q = 0; q < 4; ++q) {
      const int unit = (q * 4 + wid) * 64 + lane;  // 16B unit within tile
      const int r = unit >> 3;                     // row 0..127
      const int c = (unit & 7) << 3;               // col 0..56 step 8
      gl_lds16(Abase + (size_t)r * KDIM + ks * 64 + c,
               (char*)&sA[buf][0] + (size_t)(q * 4 + wid) * 1024);
      gl_lds16(Bbase + (size_t)r * KDIM + ks * 64 + c,
               (char*)&sB[buf][0] + (size_t)(q * 4 + wid) * 1024);
    }
  };

  stage(0, 0);

#pragma unroll
  for (int ks = 0; ks < 4; ++ks) {
    const int buf = ks & 1;
    __syncthreads();                    // drains vmcnt: buf staged for everyone
    if (ks < 3) stage(ks + 1, buf ^ 1); // prefetch next slab under compute

    const unsigned short* aptr =
        &sA[buf][(wr * 64 + (lane & 15)) * 64 + ((lane >> 4) << 3)];
    const unsigned short* bptr =
        &sB[buf][(wc * 64 + (lane & 15)) * 64 + ((lane >> 4) << 3)];
#pragma unroll
    for (int kk = 0; kk < 2; ++kk) {
      bf16x8 a[4], b[4];
#pragma unroll
      for (int m = 0; m < 4; ++m)
        a[m] = *(const bf16x8*)(aptr + m * 16 * 64 + kk * 32);
#pragma unroll
      for (int n = 0; n < 4; ++n)
        b[n] = *(const bf16x8*)(bptr + n * 16 * 64 + kk * 32);
#pragma unroll
      for (int m = 0; m < 4; ++m) {
        const bf16x8 ai = make_imag(a[m]);
#pragma unroll
        for (int n = 0; n < 4; ++n) {
          accre[m][n] = __builtin_amdgcn_mfma_f32_16x16x32_bf16(
              a[m], b[n], accre[m][n], 0, 0, 0);
          accim[m][n] = __builtin_amdgcn_mfma_f32_16x16x32_bf16(
              ai, b[n], accim[m][n], 0, 0, 0);
        }
      }
    }
  }

  // epilogue: sim = (re^2 + im^2) / temp ; C layout col=lane&15, row=(lane>>4)*4+reg
  const float inv_t = 1.0f / temp[0];
  const int r0 = brow * 128 + wr * 64 + ((lane >> 4) << 2);
  const int c0 = bcol * 128 + wc * 64 + (lane & 15);
#pragma unroll
  for (int m = 0; m < 4; ++m) {
#pragma unroll
    for (int n = 0; n < 4; ++n) {
      const f32x4 re = accre[m][n];
      const f32x4 im = accim[m][n];
#pragma unroll
      for (int j = 0; j < 4; ++j) {
        out[(size_t)(r0 + m * 16 + j) * T_TOKENS + (c0 + n * 16)] =
            (re[j] * re[j] + im[j] * im[j]) * inv_t;
      }
    }
  }
}

extern "C" void kernel_launch(void* const* d_in, const int* in_sizes, int n_in,
                              void* d_out, int out_size, void* d_ws, size_t ws_size,
                              hipStream_t stream) {
  const float* rx_r = (const float*)d_in[0];
  const float* rx_i = (const float*)d_in[1];
  const float* fq_r = (const float*)d_in[2];
  const float* fq_i = (const float*)d_in[3];
  const float* temp = (const float*)d_in[4];
  float* out = (float*)d_out;

  // workspace: B2 (bank, bf16 interleaved) 4MB @0 ; A2 (rx, bf16 interleaved) 4MB @4MB
  unsigned int* B2 = (unsigned int*)d_ws;
  unsigned int* A2 = (unsigned int*)((char*)d_ws + (4u << 20));

  build_bank_kernel<<<T_TOKENS, L_SEQ, 0, stream>>>(fq_r, fq_i, B2);
  build_a_kernel<<<(B_BATCH * L_SEQ) / 256, 256, 0, stream>>>(rx_r, rx_i, A2);
  gemm_kernel<<<(B_BATCH / 128) * (T_TOKENS / 128), 256, 0, stream>>>(
      (const unsigned short*)A2, (const unsigned short*)B2, temp, out);
}